// Round 8
// baseline (472.277 us; speedup 1.0000x reference)
//
#include <hip/hip_runtime.h>
#include <hip/hip_bf16.h>

// Nystrom TransLayer, MI355X. Round 12 (base: R11, 418.4us; best: R10, 410.6us):
//  - k_qkv_mfma: REVERT to R10 direct-scatter epilogue (LDS-bounce was +8.7us,
//    bank conflicts 3.1M->4.5M). XCD-chunked mapping kept.
//  - k_w3_mfma: grid (16 kc, 8 h); each block stages K/V slice ONCE and loops
//    all 4 mt (4x less K/V fetch: 131MB->33MB; was fetch-bound). QL for all
//    4 mt staged in 32KB LDS. Same partial sums -> numerics unchanged.
//  - k_attn1_mfma kept at 512-thr/128-token (R11, ~neutral).

typedef __attribute__((ext_vector_type(8))) short bf16x8;
typedef __attribute__((ext_vector_type(4))) float f32x4;

#define MFMA16(A, B, C) __builtin_amdgcn_mfma_f32_16x16x32_bf16(A, B, C, 0, 0, 0)
#define GLD16(g, l) __builtin_amdgcn_global_load_lds( \
    (const __attribute__((address_space(1))) void*)(g), \
    (__attribute__((address_space(3))) void*)(l), 16, 0, 0)

static __device__ __forceinline__ unsigned short f2b(float f) {
  __hip_bfloat16 h = __float2bfloat16(f);
  return *reinterpret_cast<unsigned short*>(&h);
}
static __device__ __forceinline__ float b2f(unsigned short u) {
  return __uint_as_float(((unsigned)u) << 16);
}

// ---------------- fused init: LayerNorm (2 rows/block) + weight converts ----------------
__global__ __launch_bounds__(256) void k_init(const float* __restrict__ x,
    const float* __restrict__ nw, const float* __restrict__ nb,
    unsigned short* __restrict__ h,
    const float* __restrict__ wq, unsigned short* __restrict__ wqb,
    const float* __restrict__ wo, unsigned short* __restrict__ wob) {
  const int b = blockIdx.x;
  const int t = threadIdx.x;
  if (b < 8192) {
    const int row = b * 2 + (t >> 7);
    const int tl = t & 127;
    const float4 xv = ((const float4*)(x + (size_t)row * 512))[tl];
    float s  = xv.x + xv.y + xv.z + xv.w;
    float sq = xv.x*xv.x + xv.y*xv.y + xv.z*xv.z + xv.w*xv.w;
    #pragma unroll
    for (int o = 32; o > 0; o >>= 1) {
      s  += __shfl_down(s, o, 64);
      sq += __shfl_down(sq, o, 64);
    }
    __shared__ float ls[4], lq[4];
    if ((t & 63) == 0) { ls[t >> 6] = s; lq[t >> 6] = sq; }
    __syncthreads();
    const int base = (t >> 7) << 1;
    s = ls[base] + ls[base + 1]; sq = lq[base] + lq[base + 1];
    const float mean = s * (1.0f / 512.0f);
    const float var  = sq * (1.0f / 512.0f) - mean * mean;
    const float rstd = rsqrtf(var + 1e-5f);
    const float4 wv = ((const float4*)nw)[tl];
    const float4 bv = ((const float4*)nb)[tl];
    ushort4 hv;
    hv.x = f2b((xv.x - mean) * rstd * wv.x + bv.x);
    hv.y = f2b((xv.y - mean) * rstd * wv.y + bv.y);
    hv.z = f2b((xv.z - mean) * rstd * wv.z + bv.z);
    hv.w = f2b((xv.w - mean) * rstd * wv.w + bv.w);
    ((ushort4*)(h + (size_t)row * 512))[tl] = hv;
  } else if (b < 8960) {
    const int i = (b - 8192) * 256 + t;
    const float4 f = ((const float4*)wq)[i];
    ushort4 u;
    u.x = f2b(f.x); u.y = f2b(f.y); u.z = f2b(f.z); u.w = f2b(f.w);
    ((ushort4*)wqb)[i] = u;
  } else {
    const int i = (b - 8960) * 256 + t;
    const float4 f = ((const float4*)wo)[i];
    ushort4 u;
    u.x = f2b(f.x); u.y = f2b(f.y); u.z = f2b(f.z); u.w = f2b(f.w);
    ((ushort4*)wob)[i] = u;
  }
}

// ---------------- QKV MFMA (R10: XCD-chunked mapping, direct scatter) ----------------
__global__ __launch_bounds__(256) void k_qkv_mfma(const unsigned short* __restrict__ A,
    const unsigned short* __restrict__ B,
    unsigned short* __restrict__ qb, unsigned short* __restrict__ kb,
    unsigned short* __restrict__ vb) {
  __shared__ unsigned short As[128 * 32];
  __shared__ unsigned short Bs[128 * 32];
  const int t = threadIdx.x;
  const int lane = t & 63, w = t >> 6;
  const int quad = lane >> 4, l15 = lane & 15;
  const int wm = (w >> 1) * 64, wn = (w & 1) * 64;
  const int bid = blockIdx.x;
  const int xcd = bid & 7, i0 = bid >> 3;      // i0: 0..191
  const int by = xcd * 16 + i0 / 12, bx = i0 % 12;
  const int m0 = by * 128, n0 = bx * 128;
  f32x4 acc[4][4];
  #pragma unroll
  for (int i = 0; i < 4; ++i)
    #pragma unroll
    for (int j = 0; j < 4; ++j) acc[i][j] = (f32x4){0.f, 0.f, 0.f, 0.f};
  for (int k0 = 0; k0 < 512; k0 += 32) {
    __syncthreads();
    #pragma unroll
    for (int c = 0; c < 2; ++c) {
      const int slot = c * 256 + t;
      const int row = slot >> 2, seg = slot & 3;
      GLD16(A + (size_t)(m0 + row) * 512 + k0 + seg * 8, As + slot * 8);
      GLD16(B + (size_t)(n0 + row) * 512 + k0 + seg * 8, Bs + slot * 8);
    }
    __syncthreads();
    bf16x8 a[4], b[4];
    #pragma unroll
    for (int i = 0; i < 4; ++i)
      a[i] = *(const bf16x8*)(As + (wm + i * 16 + l15) * 32 + quad * 8);
    #pragma unroll
    for (int j = 0; j < 4; ++j)
      b[j] = *(const bf16x8*)(Bs + (wn + j * 16 + l15) * 32 + quad * 8);
    #pragma unroll
    for (int i = 0; i < 4; ++i)
      #pragma unroll
      for (int j = 0; j < 4; ++j)
        acc[i][j] = MFMA16(a[i], b[j], acc[i][j]);
  }
  const int part = n0 >> 9;
  #pragma unroll
  for (int i = 0; i < 4; ++i)
    #pragma unroll
    for (int j = 0; j < 4; ++j)
      #pragma unroll
      for (int r = 0; r < 4; ++r) {
        const int row = m0 + wm + i * 16 + quad * 4 + r;
        const int col = n0 + wn + j * 16 + l15;
        const int rem = col & 511;
        const int hd = rem >> 6, dd = rem & 63;
        const size_t idx = ((size_t)hd * 16384 + row) * 64 + dd;
        const float val = acc[i][j][r];
        if (part == 0)      qb[idx] = f2b(val * 0.125f);
        else if (part == 1) kb[idx] = f2b(val);
        else                vb[idx] = f2b(val);
      }
}

// ---------------- k_prep: z=0 -> v transpose; z=1/2 -> q/k landmarks ----------------
__global__ __launch_bounds__(256) void k_prep(const unsigned short* __restrict__ vb,
    unsigned short* __restrict__ vt, const unsigned short* __restrict__ qb,
    const unsigned short* __restrict__ kb, float* __restrict__ qlf,
    unsigned short* __restrict__ qlb, float* __restrict__ klf,
    unsigned short* __restrict__ klb) {
  __shared__ __align__(16) unsigned char smem[64 * 72 * 2];
  const int t = threadIdx.x;
  const int h = blockIdx.y;
  if (blockIdx.z == 0) {
    auto T = (unsigned short(*)[72])smem;
    const int n0 = blockIdx.x * 64;
    const int n = t >> 2, sg = (t & 3) * 16;
    const unsigned short* p = vb + ((size_t)(h * 16384 + n0 + n)) * 64 + sg;
    #pragma unroll
    for (int i = 0; i < 16; i += 4) {
      const ushort4 u = *(const ushort4*)(p + i);
      T[sg + i + 0][n] = u.x; T[sg + i + 1][n] = u.y;
      T[sg + i + 2][n] = u.z; T[sg + i + 3][n] = u.w;
    }
    __syncthreads();
    const int d = t >> 2, so = (t & 3) * 16;
    unsigned short* q = vt + ((size_t)(h * 64 + d)) * 16384 + n0 + so;
    #pragma unroll
    for (int i = 0; i < 16; i += 4) {
      ushort4 u;
      u.x = T[d][so + i]; u.y = T[d][so + i + 1];
      u.z = T[d][so + i + 2]; u.w = T[d][so + i + 3];
      *(ushort4*)(q + i) = u;
    }
  } else {
    auto red = (float(*)[64])smem;
    const int d = t & 63, grp = t >> 6;
    const int m = blockIdx.x;
    const unsigned short* src = (blockIdx.z == 1) ? qb : kb;
    const unsigned short* p = src + ((size_t)h * 16384 + m * 64 + grp * 16) * 64 + d;
    float s = 0.f;
    #pragma unroll
    for (int i = 0; i < 16; ++i) s += b2f(p[(size_t)i * 64]);
    red[grp][d] = s;
    __syncthreads();
    if (t < 64) {
      float v = (red[0][d] + red[1][d]) + (red[2][d] + red[3][d]);
      v *= (1.0f / 64.0f);
      const size_t oi = ((size_t)h * 256 + m) * 64 + d;
      if (blockIdx.z == 1) { qlf[oi] = v; qlb[oi] = f2b(v); }
      else                 { klf[oi] = v; klb[oi] = f2b(v); }
    }
  }
}

// ---------------- attn2 = softmax(q_l @ k_l^T) rows + atomic column sums ----------------
__global__ __launch_bounds__(256) void k_attn2(const float* __restrict__ ql,
    const float* __restrict__ kl, float* __restrict__ a2, unsigned short* __restrict__ a2b,
    float* __restrict__ csum) {
  const int i = blockIdx.x, h = blockIdx.y, j = threadIdx.x;
  __shared__ float qrow[64];
  __shared__ float wred[4];
  __shared__ float wsum[4];
  if (j < 64) qrow[j] = ql[((size_t)h * 256 + i) * 64 + j];
  __syncthreads();
  const float* kr = kl + ((size_t)h * 256 + j) * 64;
  float s = 0.f;
  #pragma unroll 8
  for (int d = 0; d < 64; ++d) s += qrow[d] * kr[d];
  float mx = s;
  #pragma unroll
  for (int o2 = 32; o2 > 0; o2 >>= 1) mx = fmaxf(mx, __shfl_xor(mx, o2, 64));
  if ((j & 63) == 0) wred[j >> 6] = mx;
  __syncthreads();
  mx = fmaxf(fmaxf(wred[0], wred[1]), fmaxf(wred[2], wred[3]));
  const float e = __expf(s - mx);
  float sm = e;
  #pragma unroll
  for (int o2 = 32; o2 > 0; o2 >>= 1) sm += __shfl_xor(sm, o2, 64);
  if ((j & 63) == 0) wsum[j >> 6] = sm;
  __syncthreads();
  sm = wsum[0] + wsum[1] + wsum[2] + wsum[3];
  const float v = e / sm;
  const size_t idx = ((size_t)h * 256 + i) * 256 + j;
  a2[idx] = v;
  a2b[idx] = f2b(v);
  atomicAdd(&csum[h * 256 + j], v);
}

// ---------------- z0: z0b = (a2^T/g) bf16, z0t = (a2/g) bf16 ----------------
__global__ __launch_bounds__(256) void k_z0(const float* __restrict__ a2,
    const float* __restrict__ csum, unsigned short* __restrict__ z0b,
    unsigned short* __restrict__ z0t) {
  __shared__ float T[64][65];
  __shared__ float wm[4];
  const int bi = blockIdx.x, bj = blockIdx.y, h = blockIdx.z;
  const int t = threadIdx.x;
  const int r = t >> 2, cseg = (t & 3) * 16;
  float m = 0.f;
  #pragma unroll
  for (int c = 0; c < 8; ++c) m = fmaxf(m, csum[c * 256 + t]);
  #pragma unroll
  for (int o2 = 32; o2 > 0; o2 >>= 1) m = fmaxf(m, __shfl_xor(m, o2, 64));
  if ((t & 63) == 0) wm[t >> 6] = m;
  __syncthreads();
  const float g = fmaxf(fmaxf(wm[0], wm[1]), fmaxf(wm[2], wm[3]));
  const float inv = 1.0f / g;
  const float* p = a2 + ((size_t)h * 256 + bj * 64 + r) * 256 + bi * 64 + cseg;
  unsigned short* qt = z0t + ((size_t)h * 256 + bj * 64 + r) * 256 + bi * 64 + cseg;
  #pragma unroll
  for (int i = 0; i < 16; i += 4) {
    const float4 f = *(const float4*)(p + i);
    T[cseg + i + 0][r] = f.x; T[cseg + i + 1][r] = f.y;
    T[cseg + i + 2][r] = f.z; T[cseg + i + 3][r] = f.w;
    ushort4 u;
    u.x = f2b(f.x * inv); u.y = f2b(f.y * inv);
    u.z = f2b(f.z * inv); u.w = f2b(f.w * inv);
    *(ushort4*)(qt + i) = u;
  }
  __syncthreads();
  unsigned short* qb_ = z0b + ((size_t)h * 256 + bi * 64 + r) * 256 + bj * 64 + cseg;
  #pragma unroll
  for (int i = 0; i < 16; i += 4) {
    ushort4 u;
    u.x = f2b(T[r][cseg + i] * inv);     u.y = f2b(T[r][cseg + i + 1] * inv);
    u.z = f2b(T[r][cseg + i + 2] * inv); u.w = f2b(T[r][cseg + i + 3] * inv);
    *(ushort4*)(qb_ + i) = u;
  }
}

// ---------------- bf16 MFMA batched GEMM for pinv iters (single-stage K=256) ----------------
__global__ __launch_bounds__(256) void k_pgemm(const unsigned short* __restrict__ A,
    const unsigned short* __restrict__ Bt, unsigned short* __restrict__ Cn,
    unsigned short* __restrict__ Ct, float* __restrict__ Cf,
    float alpha, float sdiag, int use_diag) {
  __shared__ unsigned short As[64 * 256];   // 32KB
  __shared__ unsigned short Bs[32 * 256];   // 16KB
  const int t = threadIdx.x;
  const int lane = t & 63, w = t >> 6;
  const int quad = lane >> 4, l15 = lane & 15;
  const int bn = blockIdx.x, bm = blockIdx.y, h = blockIdx.z;
  const size_t hs = (size_t)h * 65536;
  const unsigned short* Ap = A + hs + (size_t)(bm * 64) * 256;
  const unsigned short* Bp = Bt + hs + (size_t)(bn * 32) * 256;
  #pragma unroll
  for (int c = 0; c < 8; ++c) {
    const int s = c * 256 + t;
    const int row = s >> 5, pc = s & 31;
    const int lc = pc ^ (row & 7);
    GLD16(Ap + (size_t)row * 256 + lc * 8, As + s * 8);
  }
  #pragma unroll
  for (int c = 0; c < 4; ++c) {
    const int s = c * 256 + t;
    const int row = s >> 5, pc = s & 31;
    const int lc = pc ^ (row & 7);
    GLD16(Bp + (size_t)row * 256 + lc * 8, Bs + s * 8);
  }
  f32x4 acc[2];
  acc[0] = (f32x4){0.f, 0.f, 0.f, 0.f};
  acc[1] = (f32x4){0.f, 0.f, 0.f, 0.f};
  __syncthreads();
  const int arow = w * 16 + l15;
  #pragma unroll
  for (int kc = 0; kc < 8; ++kc) {
    const bf16x8 a = *(const bf16x8*)(As + arow * 256 + (((kc * 4 + quad) ^ (arow & 7)) * 8));
    #pragma unroll
    for (int j = 0; j < 2; ++j) {
      const int brow = j * 16 + l15;
      const bf16x8 b = *(const bf16x8*)(Bs + brow * 256 + (((kc * 4 + quad) ^ (brow & 7)) * 8));
      acc[j] = MFMA16(a, b, acc[j]);
    }
  }
  const int row0 = bm * 64 + w * 16 + quad * 4;
  #pragma unroll
  for (int j = 0; j < 2; ++j) {
    const int col = bn * 32 + j * 16 + l15;
    float v[4];
    #pragma unroll
    for (int r = 0; r < 4; ++r) v[r] = acc[j][r] * alpha;
    if (Cn) {
      #pragma unroll
      for (int r = 0; r < 4; ++r) Cn[hs + (size_t)(row0 + r) * 256 + col] = f2b(v[r]);
    }
    if (Cf) {
      #pragma unroll
      for (int r = 0; r < 4; ++r) Cf[hs + (size_t)(row0 + r) * 256 + col] = v[r];
    }
    ushort4 u;
    float tv[4];
    #pragma unroll
    for (int r = 0; r < 4; ++r)
      tv[r] = use_diag ? ((col == row0 + r ? sdiag : 0.f) - v[r]) : v[r];
    u.x = f2b(tv[0]); u.y = f2b(tv[1]); u.z = f2b(tv[2]); u.w = f2b(tv[3]);
    *(ushort4*)(Ct + hs + (size_t)col * 256 + row0) = u;
  }
}

// ---------------- fp32 batched 256-K GEMM, 64x32 tiles on 256 blocks ----------------
__global__ __launch_bounds__(256) void k_gemm256(const float* __restrict__ A,
    const float* __restrict__ B, float* __restrict__ C,
    float alpha, float sdiag, int use_diag) {
  A += (size_t)blockIdx.z * 65536;
  B += (size_t)blockIdx.z * 65536;
  C += (size_t)blockIdx.z * 65536;
  __shared__ float As[16][68];
  __shared__ float Bs[16][36];
  const int t = threadIdx.x, tx = t & 15, ty = t >> 4;
  const int bn = blockIdx.x, bm = blockIdx.y;
  const int lr = t >> 2, lk = (t & 3) << 2;
  const int bkr = t >> 4, bnc = (t & 15) << 1;
  float acc[4][2] = {{0.f}};
  for (int k0 = 0; k0 < 256; k0 += 16) {
    float4 a4 = *(const float4*)(A + (size_t)(bm * 64 + lr) * 256 + k0 + lk);
    float2 b2 = *(const float2*)(B + (size_t)(k0 + bkr) * 256 + bn * 32 + bnc);
    if (use_diag) {
      const int kg = k0 + bkr, ngb = bn * 32 + bnc;
      b2.x = (kg == ngb + 0 ? sdiag : 0.f) - b2.x;
      b2.y = (kg == ngb + 1 ? sdiag : 0.f) - b2.y;
    }
    __syncthreads();
    As[lk+0][lr] = a4.x; As[lk+1][lr] = a4.y; As[lk+2][lr] = a4.z; As[lk+3][lr] = a4.w;
    Bs[bkr][bnc] = b2.x; Bs[bkr][bnc + 1] = b2.y;
    __syncthreads();
    #pragma unroll
    for (int kq = 0; kq < 16; ++kq) {
      const float4 av = *(const float4*)&As[kq][ty << 2];
      const float bx_ = Bs[kq][tx << 1], by_ = Bs[kq][(tx << 1) + 1];
      acc[0][0] += av.x * bx_; acc[0][1] += av.x * by_;
      acc[1][0] += av.y * bx_; acc[1][1] += av.y * by_;
      acc[2][0] += av.z * bx_; acc[2][1] += av.z * by_;
      acc[3][0] += av.w * bx_; acc[3][1] += av.w * by_;
    }
  }
  #pragma unroll
  for (int ii = 0; ii < 4; ++ii)
    #pragma unroll
    for (int jj = 0; jj < 2; ++jj)
      C[(size_t)(bm * 64 + (ty << 2) + ii) * 256 + bn * 32 + (tx << 1) + jj] =
          alpha * acc[ii][jj];
}

// ---------------- k_gemmD: D = zfin @ diag(1/lsum) @ W, written transposed bf16 ----------------
__global__ __launch_bounds__(256) void k_gemmD(const float* __restrict__ A,
    const float* __restrict__ B, const float* __restrict__ rs,
    unsigned short* __restrict__ dtb) {
  __shared__ float Asf[16 * 68];
  __shared__ float Bsf[16 * 68];
  const int bm = blockIdx.x, h = blockIdx.y;
  A += (size_t)h * 65536;     // zfin [256][256]
  B += (size_t)h * 16384;     // W    [256][64]
  rs += (size_t)h * 256;      // lsum [256]
  const int t = threadIdx.x, tx = t & 15, ty = t >> 4;
  const int lr = t >> 2, lk = (t & 3) << 2;
  const int bkr = t >> 4, bnc = (t & 15) << 2;
  float acc[4][4] = {{0.f}};
  for (int k0 = 0; k0 < 256; k0 += 16) {
    float4 a4 = *(const float4*)(A + (size_t)(bm * 64 + lr) * 256 + k0 + lk);
    float4 b4 = *(const float4*)(B + (size_t)(k0 + bkr) * 64 + bnc);
    const float rv = 1.0f / rs[k0 + bkr];
    b4.x *= rv; b4.y *= rv; b4.z *= rv; b4.w *= rv;
    __syncthreads();
    Asf[(lk + 0) * 68 + lr] = a4.x; Asf[(lk + 1) * 68 + lr] = a4.y;
    Asf[(lk + 2) * 68 + lr] = a4.z; Asf[(lk + 3) * 68 + lr] = a4.w;
    *(float4*)&Bsf[bkr * 68 + bnc] = b4;
    __syncthreads();
    #pragma unroll
    for (int kq = 0; kq < 16; ++kq) {
      const float4 av = *(const float4*)&Asf[kq * 68 + (ty << 2)];
      const float4 bv = *(const float4*)&Bsf[kq * 68 + (tx << 2)];
      acc[0][0] += av.x*bv.x; acc[0][1] += av.x*bv.y; acc[0][2] += av.x*bv.z; acc[0][3] += av.x*bv.w;
      acc[1][0] += av.y*bv.x; acc[1][1] += av.y*bv.y; acc[1][2] += av.y*bv.z; acc[1][3] += av.y*bv.w;
      acc[2][0] += av.z*bv.x; acc[2][1] += av.z*bv.y; acc[2][2] += av.z*bv.z; acc[2][3] += av.z*bv.w;
      acc[3][0] += av.w*bv.x; acc[3][1] += av.w*bv.y; acc[3][2] += av.w*bv.z; acc[3][3] += av.w*bv.w;
    }
  }
  #pragma unroll
  for (int ii = 0; ii < 4; ++ii)
    #pragma unroll
    for (int jj = 0; jj < 4; ++jj)
      dtb[(size_t)(h * 64 + (tx << 2) + jj) * 256 + bm * 64 + (ty << 2) + ii] =
          f2b(acc[ii][jj]);
}

// ---------------- fused attn3@v MFMA: W += exp(ql@k^T)@v ----------------
// grid (16 kc, 8 h): each block stages its 1024-token K/V slice ONCE and loops
// all 4 mt (QL for all 256 landmarks held in 32KB LDS). P write->read is
// intra-wave (rows w*16..w*16+15), no barrier needed there.
__global__ __launch_bounds__(256) void k_w3_mfma(const unsigned short* __restrict__ qlb,
    const unsigned short* __restrict__ kb, const unsigned short* __restrict__ vt,
    float* __restrict__ W, float* __restrict__ lsum) {
  __shared__ unsigned short QLs[256 * 64];  // 32KB: all 4 mt
  __shared__ unsigned short Ks [64 * 64];   // 8KB
  __shared__ unsigned short Vts[64 * 64];   // 8KB
  __shared__ unsigned short Ps [64 * 64];   // 8KB (per-wave rows, intra-wave)
  const int t = threadIdx.x;
  const int lane = t & 63, w = t >> 6;
  const int quad = lane >> 4, l15 = lane & 15;
  const int kc = blockIdx.x, h = blockIdx.y;
  // stage all 256 QL rows (2048 slots)
  #pragma unroll
  for (int c = 0; c < 8; ++c) {
    const int slot = c * 256 + t;
    const int row = slot >> 3, pc = slot & 7, lc = pc ^ (row & 7);
    GLD16(qlb + ((size_t)(h * 256 + row)) * 64 + lc * 8, QLs + slot * 8);
  }
  __syncthreads();
  const int arow = w * 16 + l15;
  f32x4 wacc[4][4];
  #pragma unroll
  for (int mt = 0; mt < 4; ++mt)
    #pragma unroll
    for (int dt = 0; dt < 4; ++dt) wacc[mt][dt] = (f32x4){0.f, 0.f, 0.f, 0.f};
  float lacc[4][4];
  #pragma unroll
  for (int mt = 0; mt < 4; ++mt)
    #pragma unroll
    for (int r = 0; r < 4; ++r) lacc[mt][r] = 0.f;
  for (int ss = 0; ss < 16; ++ss) {
    const int n0 = kc * 1024 + ss * 64;
    __syncthreads();
    #pragma unroll
    for (int c = 0; c < 2; ++c) {
      const int slot = c * 256 + t;
      const int row = slot >> 3, pc = slot & 7, lc = pc ^ (row & 7);
      GLD16(kb + ((size_t)(h * 16384 + n0 + row)) * 64 + lc * 8, Ks + slot * 8);
      GLD16(vt + ((size_t)(h * 64 + row)) * 16384 + n0 + lc * 8, Vts + slot * 8);
    }
    __syncthreads();
    #pragma unroll 1
    for (int mt = 0; mt < 4; ++mt) {
      const int qrow = mt * 64 + arow;
      const bf16x8 aq0 = *(const bf16x8*)(QLs + qrow * 64 + ((quad    ) ^ (qrow & 7)) * 8);
      const bf16x8 aq1 = *(const bf16x8*)(QLs + qrow * 64 + ((quad + 4) ^ (qrow & 7)) * 8);
      f32x4 s[4];
      #pragma unroll
      for (int j = 0; j < 4; ++j) {
        s[j] = (f32x4){0.f, 0.f, 0.f, 0.f};
        const int brow = j * 16 + l15;
        const bf16x8 b0 = *(const bf16x8*)(Ks + brow * 64 + ((quad    ) ^ (brow & 7)) * 8);
        const bf16x8 b1 = *(const bf16x8*)(Ks + brow * 64 + ((quad + 4) ^ (brow & 7)) * 8);
        s[j] = MFMA16(aq0, b0, s[j]);
        s[j] = MFMA16(aq1, b1, s[j]);
      }
      #pragma unroll
      for (int j = 0; j < 4; ++j)
        #pragma unroll
        for (int r = 0; r < 4; ++r) {
          const float e = __expf(s[j][r]);
          lacc[mt][r] += e;
          const int prow = w * 16 + quad * 4 + r, pcol = j * 16 + l15;
          Ps[prow * 64 + (((pcol >> 3) ^ (prow & 7)) << 3) + (pcol & 7)] = f2b(e);
        }
      // P write->read is intra-wave; compiler's lgkmcnt covers the dependency
      const bf16x8 ap0 = *(const bf16x8*)(Ps + arow * 64 + ((quad    ) ^ (arow & 7)) * 8);
      const bf16x8 ap1 = *(const bf16x8*)(Ps + arow * 64 + ((quad + 4) ^ (arow & 7)) * 8);
      #pragma unroll
      for (int dt = 0; dt < 4; ++dt) {
        const int brow = dt * 16 + l15;
        const bf16x8 b0 = *(const bf16x8*)(Vts + brow * 64 + ((quad    ) ^ (brow & 7)) * 8);
        const bf16x8 b1 = *(const bf16x8*)(Vts + brow * 64 + ((quad + 4) ^ (brow & 7)) * 8);
        wacc[mt][dt] = MFMA16(ap0, b0, wacc[mt][dt]);
        wacc[mt][dt] = MFMA16(ap1, b1, wacc[mt][dt]);
      }
    }
  }
  #pragma unroll
  for (int mt = 0; mt < 4; ++mt) {
    #pragma unroll
    for (int dt = 0; dt < 4; ++dt)
      #pragma unroll
      for (int r = 0; r < 4; ++r)
        atomicAdd(&W[((size_t)(h * 256 + mt * 64 + w * 16 + quad * 4 + r)) * 64 + dt * 16 + l15],
                  wacc[mt][dt][r]);
    #pragma unroll
    for (int r = 0; r < 4; ++r) {
      float lv = lacc[mt][r];
      #pragma unroll
      for (int msk = 1; msk < 16; msk <<= 1) lv += __shfl_xor(lv, msk, 64);
      if (l15 == 0)
        atomicAdd(&lsum[h * 256 + mt * 64 + w * 16 + quad * 4 + r], lv);
    }
  }
}

// ---------------- fused attn1@D + conv-via-MFMA: 512 thr, 128 tokens/block ----------------
__global__ __launch_bounds__(512) void k_attn1_mfma(const unsigned short* __restrict__ qb,
    const unsigned short* __restrict__ klb, const unsigned short* __restrict__ dtb,
    const unsigned short* __restrict__ vt, const float* __restrict__ cw,
    unsigned short* __restrict__ o) {
  __shared__ __align__(16) unsigned short Wb[2][6144]; // Q staging (16KB) then 2 conv bands
  __shared__ unsigned short Ks[4096];    // 8KB
  __shared__ unsigned short Ds[4096];    // 8KB
  __shared__ unsigned short Ps[2][4096]; // 16KB
  __shared__ float Wsm[33];
  const int t = threadIdx.x;
  const int lane = t & 63, w = t >> 6;
  const int g = w >> 2, wl = w & 3;
  const int quad = lane >> 4, l15 = lane & 15;
  const int bt = blockIdx.x, h = blockIdx.y;
  const int n0 = bt * 128;
  if (t < 33) Wsm[t] = cw[h * 33 + t];
  unsigned short* WbF = &Wb[0][0];
  #pragma unroll
  for (int c = 0; c < 2; ++c) {
    const int slot = c * 512 + t;
    const int row = slot >> 3, pc = slot & 7, lc = pc ^ (row & 7);
    GLD16(qb + ((size_t)(h * 16384 + n0 + row)) * 64 + lc * 8, WbF + slot * 8);
  }
  __syncthreads();
  const int arow = wl * 16 + l15;
  const int qrow = g * 64 + arow;
  const bf16x8 aq0 = *(const bf16x8*)(WbF + qrow * 64 + ((quad    ) ^ (qrow & 7)) * 8);
  const bf16x8 aq1 = *(const bf16x8*)(WbF + qrow * 64 + ((quad + 4) ^ (qrow & 7)) * 8);
  __syncthreads();
  {
    const int gg = t >> 8;
    const int tl = t & 255;
    const int n = tl >> 2;
    const int gb = (tl & 3) * 24;
    #pragma unroll
    for (int i = 0; i < 24; ++i) {
      const int gc = gb + i;
      const int j = gc - n;
      const int src = n0 + gg * 64 - 16 + gc;
      const float val = (j >= 0 && j <= 32 && src >= 0 && src < 16384) ? Wsm[j] : 0.f;
      Wb[gg][n * 96 + (((gc >> 3) ^ (n & 3)) << 3) + (gc & 7)] = f2b(val);
    }
  }
  __syncthreads();
  f32x4 cacc[4];
  #pragma unroll
  for (int dt = 0; dt < 4; ++dt) cacc[dt] = (f32x4){0.f, 0.f, 0.f, 0.f};
  #pragma unroll
  for (int kcc = 0; kcc < 3; ++kcc) {
    const bf16x8 a = *(const bf16x8*)(&Wb[g][0] + arow * 96 + (((kcc * 4 + quad) ^ (arow & 3)) << 3));
    int off = n0 + g * 64 - 16 + kcc * 32 + quad * 8;
    off = off < 0 ? 0 : (off > 16376 ? 16376 : off);
    #pragma unroll
    for (int dt = 0; dt < 4; ++dt) {
      const bf16x8 b = *(const bf16x8*)(vt + ((size_t)(h * 64 + dt * 16 + l15)) * 16384 + off);
      cacc[dt] = MFMA16(a, b, cacc[dt]);
    }
  }
  f32x4 oacc[4];
  #pragma unroll
  for (int dt = 0; dt < 4; ++dt) oacc[dt] = (f32x4){0.f, 0.f, 0.f, 0.f};
  float lacc[4] = {0.f, 0.f, 0.f, 0.f};
  for (int mc = 0; mc < 4; ++mc) {
    const int m0 = mc * 64;
    __syncthreads();
    {
      const int row = t >> 3, pc = t & 7, lc = pc ^ (row & 7);
      GLD16(klb + ((size_t)(h * 256 + m0 + row)) * 64 + lc * 8, Ks + t * 8);
      GLD16(dtb + ((size_t)(h * 64 + row)) * 256 + m0 + lc * 8, Ds + t * 8);
    }
    __syncthreads();
    f32x4 s[4];
    #pragma unroll
    for (int j = 0; j < 4; ++j) {
      s[j] = (f32x4){0.f, 0.f, 0.f, 0.f};
      const int brow = j * 16 + l15;
      const bf16x8 b0 = *(const bf16x8*)(Ks + brow * 64 + ((quad    ) ^ (brow & 7)) * 8);
      const bf16x8 b1 = *(const bf16x8*)(Ks + brow * 64 + ((quad + 4) ^ (brow & 7)) * 8);
      s[j] = MFMA16(aq0, b0, s[j]);
      s[j] = MFMA16(aq1, b1, s[j]);
    }
    #pragma unroll
    for (int j = 0; j < 4; ++j)
      #pragma unroll
      for (int r = 0; r < 4; ++r) {
        const float e = __expf(s[j][r]);
        lacc[r] += e;
        const int prow = wl * 16 + quad * 4 + r, pcol = j * 16 + l15;
        Ps[g][prow * 64 + (((pcol >> 3) ^ (prow & 7)) << 3) + (pcol & 7)] = f2b(e);
      }
    __syncthreads();
    const bf16x8 ap0 = *(const bf16x8*)(&Ps[g][0] + arow * 64 + ((quad    ) ^ (arow & 7)) * 8);
    const bf16x8 ap1 = *(const bf16x8*)(&Ps[g][0] + arow * 64 + ((quad + 4) ^ (arow & 7)) * 8);
    #pragma unroll
    for (int dt = 0; dt < 4; ++dt) {
      const int brow = dt * 16 + l15;
      const bf16x8 b0 = *(const bf16x8*)(Ds + brow * 64 + ((quad    ) ^ (brow & 7)) * 8);
      const bf16x8 b1 = *(const bf16x8*)(Ds + brow * 64 + ((quad + 4) ^ (brow & 7)) * 8);
      oacc[dt] = MFMA16(ap0, b0, oacc[dt]);
      oacc[dt] = MFMA16(ap1, b1, oacc[dt]);
    }
  }
  #pragma unroll
  for (int r = 0; r < 4; ++r)
    #pragma unroll
    for (int msk = 1; msk < 16; msk <<= 1) lacc[r] += __shfl_xor(lacc[r], msk, 64);
  #pragma unroll
  for (int dt = 0; dt < 4; ++dt)
    #pragma unroll
    for (int r = 0; r < 4; ++r) {
      const float val = oacc[dt][r] / lacc[r] + cacc[dt][r];
      o[((size_t)(n0 + g * 64 + wl * 16 + quad * 4 + r)) * 512 + h * 64 + dt * 16 + l15] = f2b(val);
    }
}

// ---------------- out MFMA (R4 body + XCD-chunked mapping) ----------------
__global__ __launch_bounds__(256) void k_out_mfma(const unsigned short* __restrict__ A,
    const unsigned short* __restrict__ B, const float* __restrict__ bias,
    const float* __restrict__ xres, float* __restrict__ out) {
  __shared__ unsigned short As[128 * 32];
  __shared__ unsigned short Bs[128 * 32];
  const int t = threadIdx.x;
  const int lane = t & 63, w = t >> 6;
  const int quad = lane >> 4, l15 = lane & 15;
  const int wm = (w >> 1) * 64, wn = (w & 1) * 64;
  const int bid = blockIdx.x;                  // 512 blocks
  const int xcd = bid & 7, i0 = bid >> 3;      // i0: 0..63
  const int by = xcd * 16 + (i0 >> 2), bx = i0 & 3;
  const int m0 = by * 128, n0 = bx * 128;
  f32x4 acc[4][4];
  #pragma unroll
  for (int i = 0; i < 4; ++i)
    #pragma unroll
    for (int j = 0; j < 4; ++j) acc[i][j] = (f32x4){0.f, 0.f, 0.f, 0.f};
  for (int k0 = 0; k0 < 512; k0 += 32) {
    __syncthreads();
    #pragma unroll
    for (int c = 0; c < 2; ++c) {
      const int slot = c * 256 + t;
      const int row = slot >> 2, seg = slot & 3;
      GLD16(A + (size_t)(m0 + row) * 512 + k0 + seg * 8, As + slot * 8);
      GLD16(B + (size_t)(n0 + row) * 512 + k0 + seg * 8, Bs + slot * 8);
    }
    __syncthreads();
    bf16x8 a[4], b[4];
    #pragma unroll
    for (int i = 0; i < 4; ++i)
      a[i] = *(const bf16x8*)(As + (wm + i * 16 + l15) * 32 + quad * 8);
    #pragma unroll
    for (int j = 0; j < 4; ++j)
      b[j] = *(const bf16x8*)(Bs + (wn + j * 16 + l15) * 32 + quad * 8);
    #pragma unroll
    for (int i = 0; i < 4; ++i)
      #pragma unroll
      for (int j = 0; j < 4; ++j)
        acc[i][j] = MFMA16(a[i], b[j], acc[i][j]);
  }
  #pragma unroll
  for (int i = 0; i < 4; ++i)
    #pragma unroll
    for (int j = 0; j < 4; ++j)
      #pragma unroll
      for (int r = 0; r < 4; ++r) {
        const int row = m0 + wm + i * 16 + quad * 4 + r;
        const int col = n0 + wn + j * 16 + l15;
        out[(size_t)row * 512 + col] = acc[i][j][r] + bias[col] + xres[(size_t)row * 512 + col];
      }
}

extern "C" void kernel_launch(void* const* d_in, const int* in_sizes, int n_in,
                              void* d_out, int out_size, void* d_ws, size_t ws_size,
                              hipStream_t stream) {
  const float* x      = (const float*)d_in[0];
  const float* norm_w = (const float*)d_in[1];
  const float* norm_b = (const float*)d_in[2];
  const float* w_qkv  = (const float*)d_in[3];
  const float* w_out  = (const float*)d_in[4];
  const float* b_out  = (const float*)d_in[5];
  const float* conv_w = (const float*)d_in[6];
  float* out = (float*)d_out;

  char* cur = (char*)d_ws;
  auto alloc = [&](size_t bytes) -> char* {
    char* p = cur;
    cur += (bytes + 255) & ~(size_t)255;
    return p;
  };
  const size_t NB = (size_t)16384 * 512;
  const size_t LM = (size_t)8 * 256 * 64;
  const size_t SQ = (size_t)8 * 256 * 256;

  unsigned short* h_b  = (unsigned short*)alloc(NB * 2);
  unsigned short* wq_b = (unsigned short*)alloc((size_t)1536 * 512 * 2);
  unsigned short* wo_b = (unsigned short*)alloc((size_t)512 * 512 * 2);
  unsigned short* qb   = (unsigned short*)alloc(NB * 2);
  unsigned short* kb   = (unsigned short*)alloc(NB * 2);
  unsigned short* vb   = (unsigned short*)alloc(NB * 2);
  unsigned short* vt   = (unsigned short*)alloc(NB * 2);
  float*          qlf  = (float*)alloc(LM * 4);
  float*          klf  = (float*)alloc(LM * 4);
  unsigned short* qlb  = (unsigned short*)alloc(LM * 2);
  unsigned short* klb  = (unsigned short*)alloc(LM * 2);
  float*          a2   = (float*)alloc(SQ * 4);
  unsigned short* a2b  = (unsigned short*)alloc(SQ * 2);
  unsigned short* z0b  = (unsigned short*)alloc(SQ * 2);
  unsigned short* z0t  = (unsigned short*)alloc(SQ * 2);
  unsigned short* Pn   = (unsigned short*)alloc(SQ * 2);
  unsigned short* Pt   = (unsigned short*)alloc(SQ * 2);
  unsigned short* Q1t  = (unsigned short*)alloc(SQ * 2);
  unsigned short* Q2t  = (unsigned short*)alloc(SQ * 2);
  unsigned short* zp0n = (unsigned short*)alloc(SQ * 2);
  unsigned short* zp0t = (unsigned short*)alloc(SQ * 2);
  unsigned short* zp1n = (unsigned short*)alloc(SQ * 2);
  unsigned short* zp1t = (unsigned short*)alloc(SQ * 2);
  float*          zf5  = (float*)alloc(SQ * 4);
  float*          zfin = (float*)alloc(SQ * 4);
  float*          Pp   = (float*)alloc(SQ * 4);
  float*          Q1   = (float*)alloc(SQ * 4);
  float*          Q2   = (float*)alloc(SQ * 4);
  float*          W    = (float*)alloc(LM * 4 + 4096 * 4);
  float*          lsum = W + LM;
  float*          csum = W + LM + 2048;
  unsigned short* dtb  = (unsigned short*)alloc(LM * 2);
  unsigned short* o_b  = (unsigned short*)alloc(NB * 2);

  hipMemsetAsync(W, 0, (LM + 4096) * sizeof(float), stream);
  k_init<<<9216, 256, 0, stream>>>(x, norm_w, norm_b, h_b, w_qkv, wq_b, w_out, wo_b);
  k_qkv_mfma<<<1536, 256, 0, stream>>>(h_b, wq_b, qb, kb, vb);
  k_prep<<<dim3(256, 8, 3), 256, 0, stream>>>(vb, vt, qb, kb, qlf, qlb, klf, klb);
  k_attn2<<<dim3(256, 8), 256, 0, stream>>>(qlf, klf, a2, a2b, csum);
  k_z0<<<dim3(4, 4, 8), 256, 0, stream>>>(a2, csum, z0b, z0t);
  k_w3_mfma<<<dim3(16, 8), 256, 0, stream>>>(qlb, kb, vt, W, lsum);

  // pinv iterations 1..5 in bf16 MFMA (self-correcting; iter 6 polishes in fp32)
  unsigned short* zan = z0b; unsigned short* zat = z0t;
  for (int it = 0; it < 5; ++it) {
    unsigned short* zbn = (it & 1) ? zp1n : zp0n;
    unsigned short* zbt = (it & 1) ? zp1t : zp0t;
    k_pgemm<<<dim3(8, 4, 8), 256, 0, stream>>>(a2b, zat, Pn, Pt, nullptr, 1.f, 7.f, 1);
    k_pgemm<<<dim3(8, 4, 8), 256, 0, stream>>>(Pn, Pt, nullptr, Q1t, nullptr, 1.f, 15.f, 1);
    k_pgemm<<<dim3(8, 4, 8), 256, 0, stream>>>(Pn, Q1t, nullptr, Q2t, nullptr, 1.f, 13.f, 1);
    k_pgemm<<<dim3(8, 4, 8), 256, 0, stream>>>(zan, Q2t, zbn, zbt,
        it == 4 ? zf5 : nullptr, 0.25f, 0.f, 0);
    zan = zbn; zat = zbt;
  }
  // iter 6: fp32 polish
  k_gemm256<<<dim3(8, 4, 8), 256, 0, stream>>>(a2, zf5, Pp, 1.f, 0.f, 0);
  k_gemm256<<<dim3(8, 4, 8), 256, 0, stream>>>(Pp, Pp, Q1, 1.f, 7.f, 1);
  k_gemm256<<<dim3(8, 4, 8), 256, 0, stream>>>(Pp, Q1, Q2, 1.f, 15.f, 1);
  k_gemm256<<<dim3(8, 4, 8), 256, 0, stream>>>(zf5, Q2, zfin, 0.25f, 13.f, 1);

  // D = zfin @ diag(1/lsum) @ W, written transposed (fuses D-GEMM + transpose)
  k_gemmD<<<dim3(4, 8), 256, 0, stream>>>(zfin, W, lsum, dtb);

  k_attn1_mfma<<<dim3(128, 8), 512, 0, stream>>>(qb, klb, dtb, vt, conv_w, o_b);
  k_out_mfma<<<512, 256, 0, stream>>>(o_b, wo_b, b_out, x, out);
}

// Round 9
// 409.031 us; speedup vs baseline: 1.1546x; 1.1546x over previous
//
#include <hip/hip_runtime.h>
#include <hip/hip_bf16.h>

// Nystrom TransLayer, MI355X. Round 13 = best-known composition:
//  - k_qkv_mfma: R10 direct-scatter + XCD-chunked mapping (measured 40.9us).
//  - k_w3_mfma: REVERTED to R10/R11 grid (16,4,8) version. R12's 128-block
//    K/V-reuse variant collapsed occupancy (5%, 92us); its fetch "win" proved
//    L2 already absorbed the mt re-reads (same-XCD flat-ID spacing).
//  - k_attn1_mfma: 512-thr/128-token (R11, neutral-to-slightly-better).
//  - pinv/polish/prep/init: R10 (measured good).

typedef __attribute__((ext_vector_type(8))) short bf16x8;
typedef __attribute__((ext_vector_type(4))) float f32x4;

#define MFMA16(A, B, C) __builtin_amdgcn_mfma_f32_16x16x32_bf16(A, B, C, 0, 0, 0)
#define GLD16(g, l) __builtin_amdgcn_global_load_lds( \
    (const __attribute__((address_space(1))) void*)(g), \
    (__attribute__((address_space(3))) void*)(l), 16, 0, 0)

static __device__ __forceinline__ unsigned short f2b(float f) {
  __hip_bfloat16 h = __float2bfloat16(f);
  return *reinterpret_cast<unsigned short*>(&h);
}
static __device__ __forceinline__ float b2f(unsigned short u) {
  return __uint_as_float(((unsigned)u) << 16);
}

// ---------------- fused init: LayerNorm (2 rows/block) + weight converts ----------------
__global__ __launch_bounds__(256) void k_init(const float* __restrict__ x,
    const float* __restrict__ nw, const float* __restrict__ nb,
    unsigned short* __restrict__ h,
    const float* __restrict__ wq, unsigned short* __restrict__ wqb,
    const float* __restrict__ wo, unsigned short* __restrict__ wob) {
  const int b = blockIdx.x;
  const int t = threadIdx.x;
  if (b < 8192) {
    const int row = b * 2 + (t >> 7);
    const int tl = t & 127;
    const float4 xv = ((const float4*)(x + (size_t)row * 512))[tl];
    float s  = xv.x + xv.y + xv.z + xv.w;
    float sq = xv.x*xv.x + xv.y*xv.y + xv.z*xv.z + xv.w*xv.w;
    #pragma unroll
    for (int o = 32; o > 0; o >>= 1) {
      s  += __shfl_down(s, o, 64);
      sq += __shfl_down(sq, o, 64);
    }
    __shared__ float ls[4], lq[4];
    if ((t & 63) == 0) { ls[t >> 6] = s; lq[t >> 6] = sq; }
    __syncthreads();
    const int base = (t >> 7) << 1;
    s = ls[base] + ls[base + 1]; sq = lq[base] + lq[base + 1];
    const float mean = s * (1.0f / 512.0f);
    const float var  = sq * (1.0f / 512.0f) - mean * mean;
    const float rstd = rsqrtf(var + 1e-5f);
    const float4 wv = ((const float4*)nw)[tl];
    const float4 bv = ((const float4*)nb)[tl];
    ushort4 hv;
    hv.x = f2b((xv.x - mean) * rstd * wv.x + bv.x);
    hv.y = f2b((xv.y - mean) * rstd * wv.y + bv.y);
    hv.z = f2b((xv.z - mean) * rstd * wv.z + bv.z);
    hv.w = f2b((xv.w - mean) * rstd * wv.w + bv.w);
    ((ushort4*)(h + (size_t)row * 512))[tl] = hv;
  } else if (b < 8960) {
    const int i = (b - 8192) * 256 + t;
    const float4 f = ((const float4*)wq)[i];
    ushort4 u;
    u.x = f2b(f.x); u.y = f2b(f.y); u.z = f2b(f.z); u.w = f2b(f.w);
    ((ushort4*)wqb)[i] = u;
  } else {
    const int i = (b - 8960) * 256 + t;
    const float4 f = ((const float4*)wo)[i];
    ushort4 u;
    u.x = f2b(f.x); u.y = f2b(f.y); u.z = f2b(f.z); u.w = f2b(f.w);
    ((ushort4*)wob)[i] = u;
  }
}

// ---------------- QKV MFMA (R10: XCD-chunked mapping, direct scatter) ----------------
__global__ __launch_bounds__(256) void k_qkv_mfma(const unsigned short* __restrict__ A,
    const unsigned short* __restrict__ B,
    unsigned short* __restrict__ qb, unsigned short* __restrict__ kb,
    unsigned short* __restrict__ vb) {
  __shared__ unsigned short As[128 * 32];
  __shared__ unsigned short Bs[128 * 32];
  const int t = threadIdx.x;
  const int lane = t & 63, w = t >> 6;
  const int quad = lane >> 4, l15 = lane & 15;
  const int wm = (w >> 1) * 64, wn = (w & 1) * 64;
  const int bid = blockIdx.x;
  const int xcd = bid & 7, i0 = bid >> 3;      // i0: 0..191
  const int by = xcd * 16 + i0 / 12, bx = i0 % 12;
  const int m0 = by * 128, n0 = bx * 128;
  f32x4 acc[4][4];
  #pragma unroll
  for (int i = 0; i < 4; ++i)
    #pragma unroll
    for (int j = 0; j < 4; ++j) acc[i][j] = (f32x4){0.f, 0.f, 0.f, 0.f};
  for (int k0 = 0; k0 < 512; k0 += 32) {
    __syncthreads();
    #pragma unroll
    for (int c = 0; c < 2; ++c) {
      const int slot = c * 256 + t;
      const int row = slot >> 2, seg = slot & 3;
      GLD16(A + (size_t)(m0 + row) * 512 + k0 + seg * 8, As + slot * 8);
      GLD16(B + (size_t)(n0 + row) * 512 + k0 + seg * 8, Bs + slot * 8);
    }
    __syncthreads();
    bf16x8 a[4], b[4];
    #pragma unroll
    for (int i = 0; i < 4; ++i)
      a[i] = *(const bf16x8*)(As + (wm + i * 16 + l15) * 32 + quad * 8);
    #pragma unroll
    for (int j = 0; j < 4; ++j)
      b[j] = *(const bf16x8*)(Bs + (wn + j * 16 + l15) * 32 + quad * 8);
    #pragma unroll
    for (int i = 0; i < 4; ++i)
      #pragma unroll
      for (int j = 0; j < 4; ++j)
        acc[i][j] = MFMA16(a[i], b[j], acc[i][j]);
  }
  const int part = n0 >> 9;
  #pragma unroll
  for (int i = 0; i < 4; ++i)
    #pragma unroll
    for (int j = 0; j < 4; ++j)
      #pragma unroll
      for (int r = 0; r < 4; ++r) {
        const int row = m0 + wm + i * 16 + quad * 4 + r;
        const int col = n0 + wn + j * 16 + l15;
        const int rem = col & 511;
        const int hd = rem >> 6, dd = rem & 63;
        const size_t idx = ((size_t)hd * 16384 + row) * 64 + dd;
        const float val = acc[i][j][r];
        if (part == 0)      qb[idx] = f2b(val * 0.125f);
        else if (part == 1) kb[idx] = f2b(val);
        else                vb[idx] = f2b(val);
      }
}

// ---------------- k_prep: z=0 -> v transpose; z=1/2 -> q/k landmarks ----------------
__global__ __launch_bounds__(256) void k_prep(const unsigned short* __restrict__ vb,
    unsigned short* __restrict__ vt, const unsigned short* __restrict__ qb,
    const unsigned short* __restrict__ kb, float* __restrict__ qlf,
    unsigned short* __restrict__ qlb, float* __restrict__ klf,
    unsigned short* __restrict__ klb) {
  __shared__ __align__(16) unsigned char smem[64 * 72 * 2];
  const int t = threadIdx.x;
  const int h = blockIdx.y;
  if (blockIdx.z == 0) {
    auto T = (unsigned short(*)[72])smem;
    const int n0 = blockIdx.x * 64;
    const int n = t >> 2, sg = (t & 3) * 16;
    const unsigned short* p = vb + ((size_t)(h * 16384 + n0 + n)) * 64 + sg;
    #pragma unroll
    for (int i = 0; i < 16; i += 4) {
      const ushort4 u = *(const ushort4*)(p + i);
      T[sg + i + 0][n] = u.x; T[sg + i + 1][n] = u.y;
      T[sg + i + 2][n] = u.z; T[sg + i + 3][n] = u.w;
    }
    __syncthreads();
    const int d = t >> 2, so = (t & 3) * 16;
    unsigned short* q = vt + ((size_t)(h * 64 + d)) * 16384 + n0 + so;
    #pragma unroll
    for (int i = 0; i < 16; i += 4) {
      ushort4 u;
      u.x = T[d][so + i]; u.y = T[d][so + i + 1];
      u.z = T[d][so + i + 2]; u.w = T[d][so + i + 3];
      *(ushort4*)(q + i) = u;
    }
  } else {
    auto red = (float(*)[64])smem;
    const int d = t & 63, grp = t >> 6;
    const int m = blockIdx.x;
    const unsigned short* src = (blockIdx.z == 1) ? qb : kb;
    const unsigned short* p = src + ((size_t)h * 16384 + m * 64 + grp * 16) * 64 + d;
    float s = 0.f;
    #pragma unroll
    for (int i = 0; i < 16; ++i) s += b2f(p[(size_t)i * 64]);
    red[grp][d] = s;
    __syncthreads();
    if (t < 64) {
      float v = (red[0][d] + red[1][d]) + (red[2][d] + red[3][d]);
      v *= (1.0f / 64.0f);
      const size_t oi = ((size_t)h * 256 + m) * 64 + d;
      if (blockIdx.z == 1) { qlf[oi] = v; qlb[oi] = f2b(v); }
      else                 { klf[oi] = v; klb[oi] = f2b(v); }
    }
  }
}

// ---------------- attn2 = softmax(q_l @ k_l^T) rows + atomic column sums ----------------
__global__ __launch_bounds__(256) void k_attn2(const float* __restrict__ ql,
    const float* __restrict__ kl, float* __restrict__ a2, unsigned short* __restrict__ a2b,
    float* __restrict__ csum) {
  const int i = blockIdx.x, h = blockIdx.y, j = threadIdx.x;
  __shared__ float qrow[64];
  __shared__ float wred[4];
  __shared__ float wsum[4];
  if (j < 64) qrow[j] = ql[((size_t)h * 256 + i) * 64 + j];
  __syncthreads();
  const float* kr = kl + ((size_t)h * 256 + j) * 64;
  float s = 0.f;
  #pragma unroll 8
  for (int d = 0; d < 64; ++d) s += qrow[d] * kr[d];
  float mx = s;
  #pragma unroll
  for (int o2 = 32; o2 > 0; o2 >>= 1) mx = fmaxf(mx, __shfl_xor(mx, o2, 64));
  if ((j & 63) == 0) wred[j >> 6] = mx;
  __syncthreads();
  mx = fmaxf(fmaxf(wred[0], wred[1]), fmaxf(wred[2], wred[3]));
  const float e = __expf(s - mx);
  float sm = e;
  #pragma unroll
  for (int o2 = 32; o2 > 0; o2 >>= 1) sm += __shfl_xor(sm, o2, 64);
  if ((j & 63) == 0) wsum[j >> 6] = sm;
  __syncthreads();
  sm = wsum[0] + wsum[1] + wsum[2] + wsum[3];
  const float v = e / sm;
  const size_t idx = ((size_t)h * 256 + i) * 256 + j;
  a2[idx] = v;
  a2b[idx] = f2b(v);
  atomicAdd(&csum[h * 256 + j], v);
}

// ---------------- z0: z0b = (a2^T/g) bf16, z0t = (a2/g) bf16 ----------------
__global__ __launch_bounds__(256) void k_z0(const float* __restrict__ a2,
    const float* __restrict__ csum, unsigned short* __restrict__ z0b,
    unsigned short* __restrict__ z0t) {
  __shared__ float T[64][65];
  __shared__ float wm[4];
  const int bi = blockIdx.x, bj = blockIdx.y, h = blockIdx.z;
  const int t = threadIdx.x;
  const int r = t >> 2, cseg = (t & 3) * 16;
  float m = 0.f;
  #pragma unroll
  for (int c = 0; c < 8; ++c) m = fmaxf(m, csum[c * 256 + t]);
  #pragma unroll
  for (int o2 = 32; o2 > 0; o2 >>= 1) m = fmaxf(m, __shfl_xor(m, o2, 64));
  if ((t & 63) == 0) wm[t >> 6] = m;
  __syncthreads();
  const float g = fmaxf(fmaxf(wm[0], wm[1]), fmaxf(wm[2], wm[3]));
  const float inv = 1.0f / g;
  const float* p = a2 + ((size_t)h * 256 + bj * 64 + r) * 256 + bi * 64 + cseg;
  unsigned short* qt = z0t + ((size_t)h * 256 + bj * 64 + r) * 256 + bi * 64 + cseg;
  #pragma unroll
  for (int i = 0; i < 16; i += 4) {
    const float4 f = *(const float4*)(p + i);
    T[cseg + i + 0][r] = f.x; T[cseg + i + 1][r] = f.y;
    T[cseg + i + 2][r] = f.z; T[cseg + i + 3][r] = f.w;
    ushort4 u;
    u.x = f2b(f.x * inv); u.y = f2b(f.y * inv);
    u.z = f2b(f.z * inv); u.w = f2b(f.w * inv);
    *(ushort4*)(qt + i) = u;
  }
  __syncthreads();
  unsigned short* qb_ = z0b + ((size_t)h * 256 + bi * 64 + r) * 256 + bj * 64 + cseg;
  #pragma unroll
  for (int i = 0; i < 16; i += 4) {
    ushort4 u;
    u.x = f2b(T[r][cseg + i] * inv);     u.y = f2b(T[r][cseg + i + 1] * inv);
    u.z = f2b(T[r][cseg + i + 2] * inv); u.w = f2b(T[r][cseg + i + 3] * inv);
    *(ushort4*)(qb_ + i) = u;
  }
}

// ---------------- bf16 MFMA batched GEMM for pinv iters (single-stage K=256) ----------------
__global__ __launch_bounds__(256) void k_pgemm(const unsigned short* __restrict__ A,
    const unsigned short* __restrict__ Bt, unsigned short* __restrict__ Cn,
    unsigned short* __restrict__ Ct, float* __restrict__ Cf,
    float alpha, float sdiag, int use_diag) {
  __shared__ unsigned short As[64 * 256];   // 32KB
  __shared__ unsigned short Bs[32 * 256];   // 16KB
  const int t = threadIdx.x;
  const int lane = t & 63, w = t >> 6;
  const int quad = lane >> 4, l15 = lane & 15;
  const int bn = blockIdx.x, bm = blockIdx.y, h = blockIdx.z;
  const size_t hs = (size_t)h * 65536;
  const unsigned short* Ap = A + hs + (size_t)(bm * 64) * 256;
  const unsigned short* Bp = Bt + hs + (size_t)(bn * 32) * 256;
  #pragma unroll
  for (int c = 0; c < 8; ++c) {
    const int s = c * 256 + t;
    const int row = s >> 5, pc = s & 31;
    const int lc = pc ^ (row & 7);
    GLD16(Ap + (size_t)row * 256 + lc * 8, As + s * 8);
  }
  #pragma unroll
  for (int c = 0; c < 4; ++c) {
    const int s = c * 256 + t;
    const int row = s >> 5, pc = s & 31;
    const int lc = pc ^ (row & 7);
    GLD16(Bp + (size_t)row * 256 + lc * 8, Bs + s * 8);
  }
  f32x4 acc[2];
  acc[0] = (f32x4){0.f, 0.f, 0.f, 0.f};
  acc[1] = (f32x4){0.f, 0.f, 0.f, 0.f};
  __syncthreads();
  const int arow = w * 16 + l15;
  #pragma unroll
  for (int kc = 0; kc < 8; ++kc) {
    const bf16x8 a = *(const bf16x8*)(As + arow * 256 + (((kc * 4 + quad) ^ (arow & 7)) * 8));
    #pragma unroll
    for (int j = 0; j < 2; ++j) {
      const int brow = j * 16 + l15;
      const bf16x8 b = *(const bf16x8*)(Bs + brow * 256 + (((kc * 4 + quad) ^ (brow & 7)) * 8));
      acc[j] = MFMA16(a, b, acc[j]);
    }
  }
  const int row0 = bm * 64 + w * 16 + quad * 4;
  #pragma unroll
  for (int j = 0; j < 2; ++j) {
    const int col = bn * 32 + j * 16 + l15;
    float v[4];
    #pragma unroll
    for (int r = 0; r < 4; ++r) v[r] = acc[j][r] * alpha;
    if (Cn) {
      #pragma unroll
      for (int r = 0; r < 4; ++r) Cn[hs + (size_t)(row0 + r) * 256 + col] = f2b(v[r]);
    }
    if (Cf) {
      #pragma unroll
      for (int r = 0; r < 4; ++r) Cf[hs + (size_t)(row0 + r) * 256 + col] = v[r];
    }
    ushort4 u;
    float tv[4];
    #pragma unroll
    for (int r = 0; r < 4; ++r)
      tv[r] = use_diag ? ((col == row0 + r ? sdiag : 0.f) - v[r]) : v[r];
    u.x = f2b(tv[0]); u.y = f2b(tv[1]); u.z = f2b(tv[2]); u.w = f2b(tv[3]);
    *(ushort4*)(Ct + hs + (size_t)col * 256 + row0) = u;
  }
}

// ---------------- fp32 batched 256-K GEMM, 64x32 tiles on 256 blocks ----------------
__global__ __launch_bounds__(256) void k_gemm256(const float* __restrict__ A,
    const float* __restrict__ B, float* __restrict__ C,
    float alpha, float sdiag, int use_diag) {
  A += (size_t)blockIdx.z * 65536;
  B += (size_t)blockIdx.z * 65536;
  C += (size_t)blockIdx.z * 65536;
  __shared__ float As[16][68];
  __shared__ float Bs[16][36];
  const int t = threadIdx.x, tx = t & 15, ty = t >> 4;
  const int bn = blockIdx.x, bm = blockIdx.y;
  const int lr = t >> 2, lk = (t & 3) << 2;
  const int bkr = t >> 4, bnc = (t & 15) << 1;
  float acc[4][2] = {{0.f}};
  for (int k0 = 0; k0 < 256; k0 += 16) {
    float4 a4 = *(const float4*)(A + (size_t)(bm * 64 + lr) * 256 + k0 + lk);
    float2 b2 = *(const float2*)(B + (size_t)(k0 + bkr) * 256 + bn * 32 + bnc);
    if (use_diag) {
      const int kg = k0 + bkr, ngb = bn * 32 + bnc;
      b2.x = (kg == ngb + 0 ? sdiag : 0.f) - b2.x;
      b2.y = (kg == ngb + 1 ? sdiag : 0.f) - b2.y;
    }
    __syncthreads();
    As[lk+0][lr] = a4.x; As[lk+1][lr] = a4.y; As[lk+2][lr] = a4.z; As[lk+3][lr] = a4.w;
    Bs[bkr][bnc] = b2.x; Bs[bkr][bnc + 1] = b2.y;
    __syncthreads();
    #pragma unroll
    for (int kq = 0; kq < 16; ++kq) {
      const float4 av = *(const float4*)&As[kq][ty << 2];
      const float bx_ = Bs[kq][tx << 1], by_ = Bs[kq][(tx << 1) + 1];
      acc[0][0] += av.x * bx_; acc[0][1] += av.x * by_;
      acc[1][0] += av.y * bx_; acc[1][1] += av.y * by_;
      acc[2][0] += av.z * bx_; acc[2][1] += av.z * by_;
      acc[3][0] += av.w * bx_; acc[3][1] += av.w * by_;
    }
  }
  #pragma unroll
  for (int ii = 0; ii < 4; ++ii)
    #pragma unroll
    for (int jj = 0; jj < 2; ++jj)
      C[(size_t)(bm * 64 + (ty << 2) + ii) * 256 + bn * 32 + (tx << 1) + jj] =
          alpha * acc[ii][jj];
}

// ---------------- k_gemmD: D = zfin @ diag(1/lsum) @ W, written transposed bf16 ----------------
__global__ __launch_bounds__(256) void k_gemmD(const float* __restrict__ A,
    const float* __restrict__ B, const float* __restrict__ rs,
    unsigned short* __restrict__ dtb) {
  __shared__ float Asf[16 * 68];
  __shared__ float Bsf[16 * 68];
  const int bm = blockIdx.x, h = blockIdx.y;
  A += (size_t)h * 65536;     // zfin [256][256]
  B += (size_t)h * 16384;     // W    [256][64]
  rs += (size_t)h * 256;      // lsum [256]
  const int t = threadIdx.x, tx = t & 15, ty = t >> 4;
  const int lr = t >> 2, lk = (t & 3) << 2;
  const int bkr = t >> 4, bnc = (t & 15) << 2;
  float acc[4][4] = {{0.f}};
  for (int k0 = 0; k0 < 256; k0 += 16) {
    float4 a4 = *(const float4*)(A + (size_t)(bm * 64 + lr) * 256 + k0 + lk);
    float4 b4 = *(const float4*)(B + (size_t)(k0 + bkr) * 64 + bnc);
    const float rv = 1.0f / rs[k0 + bkr];
    b4.x *= rv; b4.y *= rv; b4.z *= rv; b4.w *= rv;
    __syncthreads();
    Asf[(lk + 0) * 68 + lr] = a4.x; Asf[(lk + 1) * 68 + lr] = a4.y;
    Asf[(lk + 2) * 68 + lr] = a4.z; Asf[(lk + 3) * 68 + lr] = a4.w;
    *(float4*)&Bsf[bkr * 68 + bnc] = b4;
    __syncthreads();
    #pragma unroll
    for (int kq = 0; kq < 16; ++kq) {
      const float4 av = *(const float4*)&Asf[kq * 68 + (ty << 2)];
      const float4 bv = *(const float4*)&Bsf[kq * 68 + (tx << 2)];
      acc[0][0] += av.x*bv.x; acc[0][1] += av.x*bv.y; acc[0][2] += av.x*bv.z; acc[0][3] += av.x*bv.w;
      acc[1][0] += av.y*bv.x; acc[1][1] += av.y*bv.y; acc[1][2] += av.y*bv.z; acc[1][3] += av.y*bv.w;
      acc[2][0] += av.z*bv.x; acc[2][1] += av.z*bv.y; acc[2][2] += av.z*bv.z; acc[2][3] += av.z*bv.w;
      acc[3][0] += av.w*bv.x; acc[3][1] += av.w*bv.y; acc[3][2] += av.w*bv.z; acc[3][3] += av.w*bv.w;
    }
  }
  #pragma unroll
  for (int ii = 0; ii < 4; ++ii)
    #pragma unroll
    for (int jj = 0; jj < 4; ++jj)
      dtb[(size_t)(h * 64 + (tx << 2) + jj) * 256 + bm * 64 + (ty << 2) + ii] =
          f2b(acc[ii][jj]);
}

// ---------------- fused attn3@v MFMA (R10/R11): W += exp(ql@k^T)@v ----------------
__global__ __launch_bounds__(256) void k_w3_mfma(const unsigned short* __restrict__ qlb,
    const unsigned short* __restrict__ kb, const unsigned short* __restrict__ vt,
    float* __restrict__ W, float* __restrict__ lsum) {
  __shared__ unsigned short QLs[64 * 64];
  __shared__ unsigned short Ks [64 * 64];
  __shared__ unsigned short Vts[64 * 64];
  __shared__ unsigned short Ps [64 * 64];
  const int t = threadIdx.x;
  const int lane = t & 63, w = t >> 6;
  const int quad = lane >> 4, l15 = lane & 15;
  const int kc = blockIdx.x, mt = blockIdx.y, h = blockIdx.z;
  #pragma unroll
  for (int c = 0; c < 2; ++c) {
    const int slot = c * 256 + t;
    const int row = slot >> 3, pc = slot & 7, lc = pc ^ (row & 7);
    GLD16(qlb + ((size_t)(h * 256 + mt * 64 + row)) * 64 + lc * 8, QLs + slot * 8);
  }
  __syncthreads();
  const int arow = w * 16 + l15;
  const bf16x8 aq0 = *(const bf16x8*)(QLs + arow * 64 + ((quad    ) ^ (arow & 7)) * 8);
  const bf16x8 aq1 = *(const bf16x8*)(QLs + arow * 64 + ((quad + 4) ^ (arow & 7)) * 8);
  f32x4 wacc[4];
  #pragma unroll
  for (int dt = 0; dt < 4; ++dt) wacc[dt] = (f32x4){0.f, 0.f, 0.f, 0.f};
  float lacc[4] = {0.f, 0.f, 0.f, 0.f};
  for (int ss = 0; ss < 16; ++ss) {
    const int n0 = kc * 1024 + ss * 64;
    __syncthreads();
    #pragma unroll
    for (int c = 0; c < 2; ++c) {
      const int slot = c * 256 + t;
      const int row = slot >> 3, pc = slot & 7, lc = pc ^ (row & 7);
      GLD16(kb + ((size_t)(h * 16384 + n0 + row)) * 64 + lc * 8, Ks + slot * 8);
      GLD16(vt + ((size_t)(h * 64 + row)) * 16384 + n0 + lc * 8, Vts + slot * 8);
    }
    __syncthreads();
    f32x4 s[4];
    #pragma unroll
    for (int j = 0; j < 4; ++j) {
      s[j] = (f32x4){0.f, 0.f, 0.f, 0.f};
      const int brow = j * 16 + l15;
      const bf16x8 b0 = *(const bf16x8*)(Ks + brow * 64 + ((quad    ) ^ (brow & 7)) * 8);
      const bf16x8 b1 = *(const bf16x8*)(Ks + brow * 64 + ((quad + 4) ^ (brow & 7)) * 8);
      s[j] = MFMA16(aq0, b0, s[j]);
      s[j] = MFMA16(aq1, b1, s[j]);
    }
    #pragma unroll
    for (int j = 0; j < 4; ++j)
      #pragma unroll
      for (int r = 0; r < 4; ++r) {
        const float e = __expf(s[j][r]);
        lacc[r] += e;
        const int prow = w * 16 + quad * 4 + r, pcol = j * 16 + l15;
        Ps[prow * 64 + (((pcol >> 3) ^ (prow & 7)) << 3) + (pcol & 7)] = f2b(e);
      }
    __syncthreads();
    const bf16x8 ap0 = *(const bf16x8*)(Ps + arow * 64 + ((quad    ) ^ (arow & 7)) * 8);
    const bf16x8 ap1 = *(const bf16x8*)(Ps + arow * 64 + ((quad + 4) ^ (arow & 7)) * 8);
    #pragma unroll
    for (int dt = 0; dt < 4; ++dt) {
      const int brow = dt * 16 + l15;
      const bf16x8 b0 = *(const bf16x8*)(Vts + brow * 64 + ((quad    ) ^ (brow & 7)) * 8);
      const bf16x8 b1 = *(const bf16x8*)(Vts + brow * 64 + ((quad + 4) ^ (brow & 7)) * 8);
      wacc[dt] = MFMA16(ap0, b0, wacc[dt]);
      wacc[dt] = MFMA16(ap1, b1, wacc[dt]);
    }
  }
  #pragma unroll
  for (int dt = 0; dt < 4; ++dt)
    #pragma unroll
    for (int r = 0; r < 4; ++r)
      atomicAdd(&W[((size_t)(h * 256 + mt * 64 + w * 16 + quad * 4 + r)) * 64 + dt * 16 + l15],
                wacc[dt][r]);
  #pragma unroll
  for (int r = 0; r < 4; ++r) {
    #pragma unroll
    for (int msk = 1; msk < 16; msk <<= 1) lacc[r] += __shfl_xor(lacc[r], msk, 64);
    if (l15 == 0)
      atomicAdd(&lsum[h * 256 + mt * 64 + w * 16 + quad * 4 + r], lacc[r]);
  }
}

// ---------------- fused attn1@D + conv-via-MFMA: 512 thr, 128 tokens/block ----------------
__global__ __launch_bounds__(512) void k_attn1_mfma(const unsigned short* __restrict__ qb,
    const unsigned short* __restrict__ klb, const unsigned short* __restrict__ dtb,
    const unsigned short* __restrict__ vt, const float* __restrict__ cw,
    unsigned short* __restrict__ o) {
  __shared__ __align__(16) unsigned short Wb[2][6144]; // Q staging (16KB) then 2 conv bands
  __shared__ unsigned short Ks[4096];    // 8KB
  __shared__ unsigned short Ds[4096];    // 8KB
  __shared__ unsigned short Ps[2][4096]; // 16KB
  __shared__ float Wsm[33];
  const int t = threadIdx.x;
  const int lane = t & 63, w = t >> 6;
  const int g = w >> 2, wl = w & 3;
  const int quad = lane >> 4, l15 = lane & 15;
  const int bt = blockIdx.x, h = blockIdx.y;
  const int n0 = bt * 128;
  if (t < 33) Wsm[t] = cw[h * 33 + t];
  unsigned short* WbF = &Wb[0][0];
  #pragma unroll
  for (int c = 0; c < 2; ++c) {
    const int slot = c * 512 + t;
    const int row = slot >> 3, pc = slot & 7, lc = pc ^ (row & 7);
    GLD16(qb + ((size_t)(h * 16384 + n0 + row)) * 64 + lc * 8, WbF + slot * 8);
  }
  __syncthreads();
  const int arow = wl * 16 + l15;
  const int qrow = g * 64 + arow;
  const bf16x8 aq0 = *(const bf16x8*)(WbF + qrow * 64 + ((quad    ) ^ (qrow & 7)) * 8);
  const bf16x8 aq1 = *(const bf16x8*)(WbF + qrow * 64 + ((quad + 4) ^ (qrow & 7)) * 8);
  __syncthreads();
  {
    const int gg = t >> 8;
    const int tl = t & 255;
    const int n = tl >> 2;
    const int gb = (tl & 3) * 24;
    #pragma unroll
    for (int i = 0; i < 24; ++i) {
      const int gc = gb + i;
      const int j = gc - n;
      const int src = n0 + gg * 64 - 16 + gc;
      const float val = (j >= 0 && j <= 32 && src >= 0 && src < 16384) ? Wsm[j] : 0.f;
      Wb[gg][n * 96 + (((gc >> 3) ^ (n & 3)) << 3) + (gc & 7)] = f2b(val);
    }
  }
  __syncthreads();
  f32x4 cacc[4];
  #pragma unroll
  for (int dt = 0; dt < 4; ++dt) cacc[dt] = (f32x4){0.f, 0.f, 0.f, 0.f};
  #pragma unroll
  for (int kcc = 0; kcc < 3; ++kcc) {
    const bf16x8 a = *(const bf16x8*)(&Wb[g][0] + arow * 96 + (((kcc * 4 + quad) ^ (arow & 3)) << 3));
    int off = n0 + g * 64 - 16 + kcc * 32 + quad * 8;
    off = off < 0 ? 0 : (off > 16376 ? 16376 : off);
    #pragma unroll
    for (int dt = 0; dt < 4; ++dt) {
      const bf16x8 b = *(const bf16x8*)(vt + ((size_t)(h * 64 + dt * 16 + l15)) * 16384 + off);
      cacc[dt] = MFMA16(a, b, cacc[dt]);
    }
  }
  f32x4 oacc[4];
  #pragma unroll
  for (int dt = 0; dt < 4; ++dt) oacc[dt] = (f32x4){0.f, 0.f, 0.f, 0.f};
  float lacc[4] = {0.f, 0.f, 0.f, 0.f};
  for (int mc = 0; mc < 4; ++mc) {
    const int m0 = mc * 64;
    __syncthreads();
    {
      const int row = t >> 3, pc = t & 7, lc = pc ^ (row & 7);
      GLD16(klb + ((size_t)(h * 256 + m0 + row)) * 64 + lc * 8, Ks + t * 8);
      GLD16(dtb + ((size_t)(h * 64 + row)) * 256 + m0 + lc * 8, Ds + t * 8);
    }
    __syncthreads();
    f32x4 s[4];
    #pragma unroll
    for (int j = 0; j < 4; ++j) {
      s[j] = (f32x4){0.f, 0.f, 0.f, 0.f};
      const int brow = j * 16 + l15;
      const bf16x8 b0 = *(const bf16x8*)(Ks + brow * 64 + ((quad    ) ^ (brow & 7)) * 8);
      const bf16x8 b1 = *(const bf16x8*)(Ks + brow * 64 + ((quad + 4) ^ (brow & 7)) * 8);
      s[j] = MFMA16(aq0, b0, s[j]);
      s[j] = MFMA16(aq1, b1, s[j]);
    }
    #pragma unroll
    for (int j = 0; j < 4; ++j)
      #pragma unroll
      for (int r = 0; r < 4; ++r) {
        const float e = __expf(s[j][r]);
        lacc[r] += e;
        const int prow = wl * 16 + quad * 4 + r, pcol = j * 16 + l15;
        Ps[g][prow * 64 + (((pcol >> 3) ^ (prow & 7)) << 3) + (pcol & 7)] = f2b(e);
      }
    __syncthreads();
    const bf16x8 ap0 = *(const bf16x8*)(&Ps[g][0] + arow * 64 + ((quad    ) ^ (arow & 7)) * 8);
    const bf16x8 ap1 = *(const bf16x8*)(&Ps[g][0] + arow * 64 + ((quad + 4) ^ (arow & 7)) * 8);
    #pragma unroll
    for (int dt = 0; dt < 4; ++dt) {
      const int brow = dt * 16 + l15;
      const bf16x8 b0 = *(const bf16x8*)(Ds + brow * 64 + ((quad    ) ^ (brow & 7)) * 8);
      const bf16x8 b1 = *(const bf16x8*)(Ds + brow * 64 + ((quad + 4) ^ (brow & 7)) * 8);
      oacc[dt] = MFMA16(ap0, b0, oacc[dt]);
      oacc[dt] = MFMA16(ap1, b1, oacc[dt]);
    }
  }
  #pragma unroll
  for (int r = 0; r < 4; ++r)
    #pragma unroll
    for (int msk = 1; msk < 16; msk <<= 1) lacc[r] += __shfl_xor(lacc[r], msk, 64);
  #pragma unroll
  for (int dt = 0; dt < 4; ++dt)
    #pragma unroll
    for (int r = 0; r < 4; ++r) {
      const float val = oacc[dt][r] / lacc[r] + cacc[dt][r];
      o[((size_t)(n0 + g * 64 + wl * 16 + quad * 4 + r)) * 512 + h * 64 + dt * 16 + l15] = f2b(val);
    }
}

// ---------------- out MFMA (R4 body + XCD-chunked mapping) ----------------
__global__ __launch_bounds__(256) void k_out_mfma(const unsigned short* __restrict__ A,
    const unsigned short* __restrict__ B, const float* __restrict__ bias,
    const float* __restrict__ xres, float* __restrict__ out) {
  __shared__ unsigned short As[128 * 32];
  __shared__ unsigned short Bs[128 * 32];
  const int t = threadIdx.x;
  const int lane = t & 63, w = t >> 6;
  const int quad = lane >> 4, l15 = lane & 15;
  const int wm = (w >> 1) * 64, wn = (w & 1) * 64;
  const int bid = blockIdx.x;                  // 512 blocks
  const int xcd = bid & 7, i0 = bid >> 3;      // i0: 0..63
  const int by = xcd * 16 + (i0 >> 2), bx = i0 & 3;
  const int m0 = by * 128, n0 = bx * 128;
  f32x4 acc[4][4];
  #pragma unroll
  for (int i = 0; i < 4; ++i)
    #pragma unroll
    for (int j = 0; j < 4; ++j) acc[i][j] = (f32x4){0.f, 0.f, 0.f, 0.f};
  for (int k0 = 0; k0 < 512; k0 += 32) {
    __syncthreads();
    #pragma unroll
    for (int c = 0; c < 2; ++c) {
      const int slot = c * 256 + t;
      const int row = slot >> 2, seg = slot & 3;
      GLD16(A + (size_t)(m0 + row) * 512 + k0 + seg * 8, As + slot * 8);
      GLD16(B + (size_t)(n0 + row) * 512 + k0 + seg * 8, Bs + slot * 8);
    }
    __syncthreads();
    bf16x8 a[4], b[4];
    #pragma unroll
    for (int i = 0; i < 4; ++i)
      a[i] = *(const bf16x8*)(As + (wm + i * 16 + l15) * 32 + quad * 8);
    #pragma unroll
    for (int j = 0; j < 4; ++j)
      b[j] = *(const bf16x8*)(Bs + (wn + j * 16 + l15) * 32 + quad * 8);
    #pragma unroll
    for (int i = 0; i < 4; ++i)
      #pragma unroll
      for (int j = 0; j < 4; ++j)
        acc[i][j] = MFMA16(a[i], b[j], acc[i][j]);
  }
  #pragma unroll
  for (int i = 0; i < 4; ++i)
    #pragma unroll
    for (int j = 0; j < 4; ++j)
      #pragma unroll
      for (int r = 0; r < 4; ++r) {
        const int row = m0 + wm + i * 16 + quad * 4 + r;
        const int col = n0 + wn + j * 16 + l15;
        out[(size_t)row * 512 + col] = acc[i][j][r] + bias[col] + xres[(size_t)row * 512 + col];
      }
}

extern "C" void kernel_launch(void* const* d_in, const int* in_sizes, int n_in,
                              void* d_out, int out_size, void* d_ws, size_t ws_size,
                              hipStream_t stream) {
  const float* x      = (const float*)d_in[0];
  const float* norm_w = (const float*)d_in[1];
  const float* norm_b = (const float*)d_in[2];
  const float* w_qkv  = (const float*)d_in[3];
  const float* w_out  = (const float*)d_in[4];
  const float* b_out  = (const float*)d_in[5];
  const float* conv_w = (const float*)d_in[6];
  float* out = (float*)d_out;

  char* cur = (char*)d_ws;
  auto alloc = [&](size_t bytes) -> char* {
    char* p = cur;
    cur += (bytes + 255) & ~(size_t)255;
    return p;
  };
  const size_t NB = (size_t)16384 * 512;
  const size_t LM = (size_t)8 * 256 * 64;
  const size_t SQ = (size_t)8 * 256 * 256;

  unsigned short* h_b  = (unsigned short*)alloc(NB * 2);
  unsigned short* wq_b = (unsigned short*)alloc((size_t)1536 * 512 * 2);
  unsigned short* wo_b = (unsigned short*)alloc((size_t)512 * 512 * 2);
  unsigned short* qb   = (unsigned short*)alloc(NB * 2);
  unsigned short* kb   = (unsigned short*)alloc(NB * 2);
  unsigned short* vb   = (unsigned short*)alloc(NB * 2);
  unsigned short* vt   = (unsigned short*)alloc(NB * 2);
  float*          qlf  = (float*)alloc(LM * 4);
  float*          klf  = (float*)alloc(LM * 4);
  unsigned short* qlb  = (unsigned short*)alloc(LM * 2);
  unsigned short* klb  = (unsigned short*)alloc(LM * 2);
  float*          a2   = (float*)alloc(SQ * 4);
  unsigned short* a2b  = (unsigned short*)alloc(SQ * 2);
  unsigned short* z0b  = (unsigned short*)alloc(SQ * 2);
  unsigned short* z0t  = (unsigned short*)alloc(SQ * 2);
  unsigned short* Pn   = (unsigned short*)alloc(SQ * 2);
  unsigned short* Pt   = (unsigned short*)alloc(SQ * 2);
  unsigned short* Q1t  = (unsigned short*)alloc(SQ * 2);
  unsigned short* Q2t  = (unsigned short*)alloc(SQ * 2);
  unsigned short* zp0n = (unsigned short*)alloc(SQ * 2);
  unsigned short* zp0t = (unsigned short*)alloc(SQ * 2);
  unsigned short* zp1n = (unsigned short*)alloc(SQ * 2);
  unsigned short* zp1t = (unsigned short*)alloc(SQ * 2);
  float*          zf5  = (float*)alloc(SQ * 4);
  float*          zfin = (float*)alloc(SQ * 4);
  float*          Pp   = (float*)alloc(SQ * 4);
  float*          Q1   = (float*)alloc(SQ * 4);
  float*          Q2   = (float*)alloc(SQ * 4);
  float*          W    = (float*)alloc(LM * 4 + 4096 * 4);
  float*          lsum = W + LM;
  float*          csum = W + LM + 2048;
  unsigned short* dtb  = (unsigned short*)alloc(LM * 2);
  unsigned short* o_b  = (unsigned short*)alloc(NB * 2);

  hipMemsetAsync(W, 0, (LM + 4096) * sizeof(float), stream);
  k_init<<<9216, 256, 0, stream>>>(x, norm_w, norm_b, h_b, w_qkv, wq_b, w_out, wo_b);
  k_qkv_mfma<<<1536, 256, 0, stream>>>(h_b, wq_b, qb, kb, vb);
  k_prep<<<dim3(256, 8, 3), 256, 0, stream>>>(vb, vt, qb, kb, qlf, qlb, klf, klb);
  k_attn2<<<dim3(256, 8), 256, 0, stream>>>(qlf, klf, a2, a2b, csum);
  k_z0<<<dim3(4, 4, 8), 256, 0, stream>>>(a2, csum, z0b, z0t);
  k_w3_mfma<<<dim3(16, 4, 8), 256, 0, stream>>>(qlb, kb, vt, W, lsum);

  // pinv iterations 1..5 in bf16 MFMA (self-correcting; iter 6 polishes in fp32)
  unsigned short* zan = z0b; unsigned short* zat = z0t;
  for (int it = 0; it < 5; ++it) {
    unsigned short* zbn = (it & 1) ? zp1n : zp0n;
    unsigned short* zbt = (it & 1) ? zp1t : zp0t;
    k_pgemm<<<dim3(8, 4, 8), 256, 0, stream>>>(a2b, zat, Pn, Pt, nullptr, 1.f, 7.f, 1);
    k_pgemm<<<dim3(8, 4, 8), 256, 0, stream>>>(Pn, Pt, nullptr, Q1t, nullptr, 1.f, 15.f, 1);
    k_pgemm<<<dim3(8, 4, 8), 256, 0, stream>>>(Pn, Q1t, nullptr, Q2t, nullptr, 1.f, 13.f, 1);
    k_pgemm<<<dim3(8, 4, 8), 256, 0, stream>>>(zan, Q2t, zbn, zbt,
        it == 4 ? zf5 : nullptr, 0.25f, 0.f, 0);
    zan = zbn; zat = zbt;
  }
  // iter 6: fp32 polish
  k_gemm256<<<dim3(8, 4, 8), 256, 0, stream>>>(a2, zf5, Pp, 1.f, 0.f, 0);
  k_gemm256<<<dim3(8, 4, 8), 256, 0, stream>>>(Pp, Pp, Q1, 1.f, 7.f, 1);
  k_gemm256<<<dim3(8, 4, 8), 256, 0, stream>>>(Pp, Q1, Q2, 1.f, 15.f, 1);
  k_gemm256<<<dim3(8, 4, 8), 256, 0, stream>>>(zf5, Q2, zfin, 0.25f, 13.f, 1);

  // D = zfin @ diag(1/lsum) @ W, written transposed (fuses D-GEMM + transpose)
  k_gemmD<<<dim3(4, 8), 256, 0, stream>>>(zfin, W, lsum, dtb);

  k_attn1_mfma<<<dim3(128, 8), 512, 0, stream>>>(qb, klb, dtb, vt, conv_w, o_b);
  k_out_mfma<<<512, 256, 0, stream>>>(o_b, wo_b, b_out, x, out);
}